// Round 23
// baseline (82.591 us; speedup 1.0000x reference)
//
#include <hip/hip_runtime.h>

#define MD   4
#define B_   4
#define C_   128
#define H_   128
#define W_   256
#define ND   9

typedef float  float4v __attribute__((ext_vector_type(4)));
typedef float  f32x4   __attribute__((ext_vector_type(4)));
typedef short  bf16x8  __attribute__((ext_vector_type(8)));
typedef unsigned int u32;
typedef u32    u32x4   __attribute__((ext_vector_type(4)));

#define TS ((size_t)B_ * H_ * 4 * W_ * 32)   // halfs per converted tensor

static __device__ __forceinline__ unsigned short f2bf(float f) {
    u32 u = __float_as_uint(f);
    u32 r = (u + 0x7fffu + ((u >> 16) & 1u)) >> 16;   // RNE
    return (unsigned short)r;
}

// ---- convert (regular loads): for t2, whose fp32 image is L3-resident ----
__global__ __launch_bounds__(256, 2)
void convert_one(const float* __restrict__ src0,
                 unsigned short* __restrict__ dst0) {
    const int bid = blockIdx.x;          // [1:0]=kc [8:2]=y [10:9]=b
    const int kc  = bid & 3;
    const int y   = (bid >> 2) & (H_ - 1);
    const int b   = bid >> 9;
    const int x   = threadIdx.x;         // 0..255
    const float* src = src0 + ((size_t)(b * C_ + kc * 32) * H_ + y) * W_ + x;
    const size_t hw = (size_t)H_ * W_;

    float f[32];
    #pragma unroll
    for (int k = 0; k < 32; ++k) f[k] = src[(size_t)k * hw];

    unsigned short* dst =
        dst0 + ((((size_t)(b * H_ + y)) * 4 + kc) * W_ + x) * 32;
    #pragma unroll
    for (int q = 0; q < 4; ++q) {
        u32x4 pk;
        #pragma unroll
        for (int j = 0; j < 4; ++j)
            pk[j] = (u32)f2bf(f[q * 8 + 2 * j]) |
                    ((u32)f2bf(f[q * 8 + 2 * j + 1]) << 16);
        *(u32x4*)(dst + q * 8) = pk;
    }
}

// ---- convert with NON-TEMPORAL loads: for t1, a read-once 128MB stream.
// nt keeps the stream from evicting the L3-resident set {t2, t2ws, t1ws,
// out} = 237MB < 256MB (R21/R22's 80us was this set blowing past L3).
// Stores are REGULAR: t1ws must allocate (mfma reads it right after).
__global__ __launch_bounds__(256, 2)
void convert_nt(const float* __restrict__ src0,
                unsigned short* __restrict__ dst0) {
    const int bid = blockIdx.x;
    const int kc  = bid & 3;
    const int y   = (bid >> 2) & (H_ - 1);
    const int b   = bid >> 9;
    const int x   = threadIdx.x;
    const float* src = src0 + ((size_t)(b * C_ + kc * 32) * H_ + y) * W_ + x;
    const size_t hw = (size_t)H_ * W_;

    float f[32];
    #pragma unroll
    for (int k = 0; k < 32; ++k)
        f[k] = __builtin_nontemporal_load(src + (size_t)k * hw);

    unsigned short* dst =
        dst0 + ((((size_t)(b * H_ + y)) * 4 + kc) * W_ + x) * 32;
    #pragma unroll
    for (int q = 0; q < 4; ++q) {
        u32x4 pk;
        #pragma unroll
        for (int j = 0; j < 4; ++j)
            pk[j] = (u32)f2bf(f[q * 8 + 2 * j]) |
                    ((u32)f2bf(f[q * 8 + 2 * j + 1]) << 16);
        *(u32x4*)(dst + q * 8) = pk;
    }
}

// ---- pass 2: banded-Gram MFMA, y-pair per wave (VERBATIM R21/R22) ----
__global__ __launch_bounds__(512, 2)
void corr_mfma5(const unsigned short* __restrict__ ws,
                float* __restrict__ out) {
    __shared__ float scr[8][2 * 16 * 33];      // 33792 B, per-wave private

    const int tid = threadIdx.x;
    const int l   = tid & 63;
    const int w   = tid >> 6;                  // 0..7
    const int bid = blockIdx.x;                // 512 blocks
    const int xcd = bid & 7;                   // 2-D XCD tiling
    const int xh  = xcd >> 2;                  // x half
    const int ypq = xcd & 3;                   // y-pair quarter
    const int rst = bid >> 3;                  // 0..63
    const int b   = rst >> 4;
    const int yp  = ypq * 16 + (rst & 15);
    const int y0  = yp * 2;
    const int ln  = l & 15;
    const int kg  = l >> 4;                    // 0..3
    const int X0  = (xh * 8 + w) * 16;         // this wave's x-tile
    const float scale = 1.0f / (float)C_;
    const bf16x8 z8 = (bf16x8)(short)0;
    const unsigned short* t1w = ws;
    const unsigned short* t2w = ws + TS;

    f32x4 aA0[ND], aA1[ND], aB0[ND], aB1[ND];
    #pragma unroll
    for (int r = 0; r < ND; ++r) {
        aA0[r] = (f32x4)0.0f; aA1[r] = (f32x4)0.0f;
        aB0[r] = (f32x4)0.0f; aB1[r] = (f32x4)0.0f;
    }

    int col0 = X0 - 8 + ln;                    // B-tile 0 column (this lane)
    int col1 = X0 + 8 + ln;                    // B-tile 1 column
    const bool ob0 = col0 < 0;
    const bool ob1 = col1 > W_ - 1;
    col0 = ob0 ? 0 : col0;
    col1 = ob1 ? W_ - 1 : col1;

    #pragma unroll
    for (int kc = 0; kc < 4; ++kc) {
        const unsigned short* a_base =
            t1w + ((((size_t)(b * H_ + y0)) * 4 + kc) * W_) * 32;
        const bf16x8 fA = *(const bf16x8*)(a_base + (size_t)(X0 + ln) * 32 + kg * 8);
        const bf16x8 fB = *(const bf16x8*)(a_base + (size_t)4 * W_ * 32
                                                  + (size_t)(X0 + ln) * 32 + kg * 8);

        #pragma unroll
        for (int r = 0; r < ND + 1; ++r) {     // staged rows y0-4 .. y0+5
            const int row = y0 + r - MD;       // wave-uniform
            if (0 <= row && row < H_) {
                const unsigned short* b_base =
                    t2w + ((((size_t)(b * H_ + row)) * 4 + kc) * W_) * 32;
                bf16x8 b0 = *(const bf16x8*)(b_base + (size_t)col0 * 32 + kg * 8);
                bf16x8 b1 = *(const bf16x8*)(b_base + (size_t)col1 * 32 + kg * 8);
                b0 = ob0 ? z8 : b0;            // zero-pad OOB x'
                b1 = ob1 ? z8 : b1;
                if (r < ND) {                  // feeds y0, dy=r
                    aA0[r] = __builtin_amdgcn_mfma_f32_16x16x32_bf16(fA, b0, aA0[r], 0, 0, 0);
                    aA1[r] = __builtin_amdgcn_mfma_f32_16x16x32_bf16(fA, b1, aA1[r], 0, 0, 0);
                }
                if (r >= 1) {                  // feeds y0+1, dy=r-1
                    aB0[r-1] = __builtin_amdgcn_mfma_f32_16x16x32_bf16(fB, b0, aB0[r-1], 0, 0, 0);
                    aB1[r-1] = __builtin_amdgcn_mfma_f32_16x16x32_bf16(fB, b1, aB1[r-1], 0, 0, 0);
                }
            }
        }
    }

    float* sw = scr[w];                        // T0 at [m*33+n], T1 at 528+..

    // ---- extraction pass 1: y0 ----
    #pragma unroll
    for (int r = 0; r < ND; ++r) {
        const int row = y0 + r - MD;
        const bool liv = (0 <= row && row < H_);
        #pragma unroll
        for (int i = 0; i < 4; ++i) {
            sw[(kg * 4 + i) * 33 + ln]       = aA0[r][i];
            sw[528 + (kg * 4 + i) * 33 + ln] = aA1[r][i];
        }
        #pragma unroll
        for (int i = 0; i < 3; ++i) {
            const int dx = i * 4 + kg;
            if (dx < ND) {
                const int m  = ln;
                const int md = m + dx;
                const int idx = (md < 12) ? (m * 33 + md + 4)
                                          : (528 + m * 33 + md - 12);
                const float v = liv ? sw[idx] * scale : 0.0f;
                out[((((size_t)b * 81) + r * ND + dx) * H_ + y0) * W_ + X0 + m] = v;
            }
        }
    }
    // ---- extraction pass 2: y0+1 ----
    #pragma unroll
    for (int r = 0; r < ND; ++r) {
        const int row = y0 + 1 + r - MD;
        const bool liv = (0 <= row && row < H_);
        #pragma unroll
        for (int i = 0; i < 4; ++i) {
            sw[(kg * 4 + i) * 33 + ln]       = aB0[r][i];
            sw[528 + (kg * 4 + i) * 33 + ln] = aB1[r][i];
        }
        #pragma unroll
        for (int i = 0; i < 3; ++i) {
            const int dx = i * 4 + kg;
            if (dx < ND) {
                const int m  = ln;
                const int md = m + dx;
                const int idx = (md < 12) ? (m * 33 + md + 4)
                                          : (528 + m * 33 + md - 12);
                const float v = liv ? sw[idx] * scale : 0.0f;
                out[((((size_t)b * 81) + r * ND + dx) * H_ + (y0 + 1)) * W_ + X0 + m] = v;
            }
        }
    }
}

// ---- fallback: proven 76us scalar kernel (R11) if ws too small ----
__global__ __launch_bounds__(9 * 64, 3)
void corr_fallback(const float* __restrict__ t1,
                   const float* __restrict__ t2,
                   float* __restrict__ out) {
    const int tid  = threadIdx.x;
    const int lane = tid & 63;
    const int w    = tid >> 6;
    const int bid  = blockIdx.x;
    const int swz  = (bid & 7) * 32 + (bid >> 3);
    const int yp   = swz & 63;
    const int b    = swz >> 6;
    const int y0   = yp * 2;
    const int half = lane >> 5;
    const int lx   = lane & 31;
    const int x0   = lx * 8;
    const int yrow = y0 + half;
    const int yy   = yrow + w - MD;
    const bool live = (0 <= yy) && (yy < H_);
    const int  yc  = yy < 0 ? 0 : (yy > H_ - 1 ? H_ - 1 : yy);
    const float sc = live ? (1.0f / (float)C_) : 0.0f;
    const bool lm  = (lx == 0);
    const bool rm  = (lx == 31);
    const int offL = lm ? 0 : -4;
    const int offR = rm ? 0 :  8;

    float acc[ND][8];
    #pragma unroll
    for (int dx = 0; dx < ND; ++dx)
        #pragma unroll
        for (int j = 0; j < 8; ++j) acc[dx][j] = 0.0f;

    const float* p1 = t1 + (((size_t)(b * C_)) * H_ + yrow) * W_ + x0;
    const float* p2 = t2 + (((size_t)(b * C_)) * H_ + yc  ) * W_ + x0;
    const size_t chstr = (size_t)H_ * W_;

    #pragma unroll 2
    for (int c = 0; c < C_; ++c) {
        const float* pc1 = p1 + (size_t)c * chstr;
        const float* pc2 = p2 + (size_t)c * chstr;
        const float4v a0 = *(const float4v*)(pc1);
        const float4v a1 = *(const float4v*)(pc1 + 4);
        float4v wl = *(const float4v*)(pc2 + offL);
        const float4v v0 = *(const float4v*)(pc2);
        const float4v v1 = *(const float4v*)(pc2 + 4);
        float4v wr = *(const float4v*)(pc2 + offR);
        #pragma unroll
        for (int q = 0; q < 4; ++q) {
            wl[q] = lm ? 0.0f : wl[q];
            wr[q] = rm ? 0.0f : wr[q];
        }
        float win[16];
        #pragma unroll
        for (int q = 0; q < 4; ++q) {
            win[q] = wl[q]; win[4 + q] = v0[q];
            win[8 + q] = v1[q]; win[12 + q] = wr[q];
        }
        #pragma unroll
        for (int dx = 0; dx < ND; ++dx)
            #pragma unroll
            for (int j = 0; j < 8; ++j) {
                const float aj = (j < 4) ? a0[j] : a1[j - 4];
                acc[dx][j] = fmaf(aj, win[dx + j], acc[dx][j]);
            }
    }

    #pragma unroll
    for (int dx = 0; dx < ND; ++dx) {
        float4v o0, o1;
        #pragma unroll
        for (int j = 0; j < 4; ++j) {
            o0[j] = acc[dx][j] * sc;
            o1[j] = acc[dx][4 + j] * sc;
        }
        const size_t oidx =
            (((size_t)(b * ND * ND) + w * ND + dx) * H_ + yrow) * W_ + x0;
        *(float4v*)&out[oidx]     = o0;
        *(float4v*)&out[oidx + 4] = o1;
    }
}

extern "C" void kernel_launch(void* const* d_in, const int* in_sizes, int n_in,
                              void* d_out, int out_size, void* d_ws, size_t ws_size,
                              hipStream_t stream) {
    const float* t1 = (const float*)d_in[0];
    const float* t2 = (const float*)d_in[1];
    float* out      = (float*)d_out;
    const size_t need = 2 * TS * sizeof(unsigned short);   // 67 MB
    if (ws_size >= need) {
        unsigned short* ws = (unsigned short*)d_ws;
        // t2 first (L3-resident, fast), then the nt-t1 stream, then MFMA.
        convert_one<<<dim3(B_ * H_ * 4), 256, 0, stream>>>(t2, ws + TS);
        convert_nt <<<dim3(B_ * H_ * 4), 256, 0, stream>>>(t1, ws);
        corr_mfma5 <<<dim3(B_ * H_), 512, 0, stream>>>(ws, out);
    } else {
        corr_fallback<<<dim3(B_ * H_ / 2), 9 * 64, 0, stream>>>(t1, t2, out);
    }
}

// Round 24
// 70.761 us; speedup vs baseline: 1.1672x; 1.1672x over previous
//
#include <hip/hip_runtime.h>

#define MD   4
#define B_   4
#define C_   128
#define H_   128
#define W_   256
#define ND   9

typedef float  float4v __attribute__((ext_vector_type(4)));
typedef float  f32x4   __attribute__((ext_vector_type(4)));
typedef short  bf16x8  __attribute__((ext_vector_type(8)));
typedef unsigned int u32;
typedef u32    u32x4   __attribute__((ext_vector_type(4)));

#define TS ((size_t)B_ * H_ * 4 * W_ * 32)   // halfs in converted t2

static __device__ __forceinline__ unsigned short f2bf(float f) {
    u32 u = __float_as_uint(f);
    u32 r = (u + 0x7fffu + ((u >> 16) & 1u)) >> 16;   // RNE
    return (unsigned short)r;
}

// ---- pass 1: t2 only -> bf16 ws (R19-exact body; L3-resident source) ----
__global__ __launch_bounds__(256, 2)
void convert_one(const float* __restrict__ src0,
                 unsigned short* __restrict__ dst0) {
    const int bid = blockIdx.x;          // [1:0]=kc [8:2]=y [10:9]=b
    const int kc  = bid & 3;
    const int y   = (bid >> 2) & (H_ - 1);
    const int b   = bid >> 9;
    const int x   = threadIdx.x;         // 0..255
    const float* src = src0 + ((size_t)(b * C_ + kc * 32) * H_ + y) * W_ + x;
    const size_t hw = (size_t)H_ * W_;

    float f[32];
    #pragma unroll
    for (int k = 0; k < 32; ++k) f[k] = src[(size_t)k * hw];

    unsigned short* dst =
        dst0 + ((((size_t)(b * H_ + y)) * 4 + kc) * W_ + x) * 32;
    #pragma unroll
    for (int q = 0; q < 4; ++q) {
        u32x4 pk;
        #pragma unroll
        for (int j = 0; j < 4; ++j)
            pk[j] = (u32)f2bf(f[q * 8 + 2 * j]) |
                    ((u32)f2bf(f[q * 8 + 2 * j + 1]) << 16);
        *(u32x4*)(dst + q * 8) = pk;
    }
}

// ---- pass 2: banded-Gram MFMA. A-path HOISTED to a prologue: all 64
// t1 dword loads + f2bf run back-to-back (convert_one-style ILP, ~17
// cyc/instr there) into 8 register fragments; the B/MFMA loop is then
// VERBATIM the 43us mfma5 loop. Same instr count as mfma3 (57us), pure
// placement change -- discriminates placement-vs-count economics.
__global__ __launch_bounds__(512, 2)
void corr_mfma6(const float* __restrict__ t1,
                const unsigned short* __restrict__ t2w,
                float* __restrict__ out) {
    __shared__ float scr[8][2 * 16 * 33];      // 33792 B, per-wave private

    const int tid = threadIdx.x;
    const int l   = tid & 63;
    const int w   = tid >> 6;                  // 0..7
    const int bid = blockIdx.x;                // 512 blocks
    const int xcd = bid & 7;                   // 2-D XCD tiling
    const int xh  = xcd >> 2;                  // x half
    const int ypq = xcd & 3;                   // y-pair quarter
    const int rst = bid >> 3;                  // 0..63
    const int b   = rst >> 4;
    const int yp  = ypq * 16 + (rst & 15);
    const int y0  = yp * 2;
    const int ln  = l & 15;
    const int kg  = l >> 4;                    // 0..3
    const int X0  = (xh * 8 + w) * 16;         // this wave's x-tile
    const float scale = 1.0f / (float)C_;
    const bf16x8 z8 = (bf16x8)(short)0;
    const size_t hw = (size_t)H_ * W_;

    // ---- A prologue: 64 back-to-back dword loads + f2bf -> 8 fragments
    bf16x8 fAk[4], fBk[4];
    {
        float avA[4][8], avB[4][8];
        #pragma unroll
        for (int kc = 0; kc < 4; ++kc) {
            const float* aspA =
                t1 + ((size_t)(b * C_ + kc * 32 + kg * 8) * H_ + y0) * W_ + X0 + ln;
            const float* aspB = aspA + W_;     // y0+1
            #pragma unroll
            for (int j = 0; j < 8; ++j) avA[kc][j] = aspA[(size_t)j * hw];
            #pragma unroll
            for (int j = 0; j < 8; ++j) avB[kc][j] = aspB[(size_t)j * hw];
        }
        #pragma unroll
        for (int kc = 0; kc < 4; ++kc)
            #pragma unroll
            for (int j = 0; j < 8; ++j) {
                fAk[kc][j] = (short)f2bf(avA[kc][j]);
                fBk[kc][j] = (short)f2bf(avB[kc][j]);
            }
    }

    f32x4 aA0[ND], aA1[ND], aB0[ND], aB1[ND];
    #pragma unroll
    for (int r = 0; r < ND; ++r) {
        aA0[r] = (f32x4)0.0f; aA1[r] = (f32x4)0.0f;
        aB0[r] = (f32x4)0.0f; aB1[r] = (f32x4)0.0f;
    }

    int col0 = X0 - 8 + ln;                    // B-tile 0 column (this lane)
    int col1 = X0 + 8 + ln;                    // B-tile 1 column
    const bool ob0 = col0 < 0;
    const bool ob1 = col1 > W_ - 1;
    col0 = ob0 ? 0 : col0;
    col1 = ob1 ? W_ - 1 : col1;

    #pragma unroll
    for (int kc = 0; kc < 4; ++kc) {
        const bf16x8 fA = fAk[kc];
        const bf16x8 fB = fBk[kc];
        #pragma unroll
        for (int r = 0; r < ND + 1; ++r) {     // staged rows y0-4 .. y0+5
            const int row = y0 + r - MD;       // wave-uniform
            if (0 <= row && row < H_) {
                const unsigned short* b_base =
                    t2w + ((((size_t)(b * H_ + row)) * 4 + kc) * W_) * 32;
                bf16x8 b0 = *(const bf16x8*)(b_base + (size_t)col0 * 32 + kg * 8);
                bf16x8 b1 = *(const bf16x8*)(b_base + (size_t)col1 * 32 + kg * 8);
                b0 = ob0 ? z8 : b0;            // zero-pad OOB x'
                b1 = ob1 ? z8 : b1;
                if (r < ND) {                  // feeds y0, dy=r
                    aA0[r] = __builtin_amdgcn_mfma_f32_16x16x32_bf16(fA, b0, aA0[r], 0, 0, 0);
                    aA1[r] = __builtin_amdgcn_mfma_f32_16x16x32_bf16(fA, b1, aA1[r], 0, 0, 0);
                }
                if (r >= 1) {                  // feeds y0+1, dy=r-1
                    aB0[r-1] = __builtin_amdgcn_mfma_f32_16x16x32_bf16(fB, b0, aB0[r-1], 0, 0, 0);
                    aB1[r-1] = __builtin_amdgcn_mfma_f32_16x16x32_bf16(fB, b1, aB1[r-1], 0, 0, 0);
                }
            }
        }
    }

    float* sw = scr[w];                        // T0 at [m*33+n], T1 at 528+..

    // ---- extraction pass 1: y0 (verbatim refcheck-passed) ----
    #pragma unroll
    for (int r = 0; r < ND; ++r) {
        const int row = y0 + r - MD;
        const bool liv = (0 <= row && row < H_);
        #pragma unroll
        for (int i = 0; i < 4; ++i) {
            sw[(kg * 4 + i) * 33 + ln]       = aA0[r][i];
            sw[528 + (kg * 4 + i) * 33 + ln] = aA1[r][i];
        }
        #pragma unroll
        for (int i = 0; i < 3; ++i) {
            const int dx = i * 4 + kg;
            if (dx < ND) {
                const int m  = ln;
                const int md = m + dx;
                const int idx = (md < 12) ? (m * 33 + md + 4)
                                          : (528 + m * 33 + md - 12);
                const float v = liv ? sw[idx] * scale : 0.0f;
                out[((((size_t)b * 81) + r * ND + dx) * H_ + y0) * W_ + X0 + m] = v;
            }
        }
    }
    // ---- extraction pass 2: y0+1 ----
    #pragma unroll
    for (int r = 0; r < ND; ++r) {
        const int row = y0 + 1 + r - MD;
        const bool liv = (0 <= row && row < H_);
        #pragma unroll
        for (int i = 0; i < 4; ++i) {
            sw[(kg * 4 + i) * 33 + ln]       = aB0[r][i];
            sw[528 + (kg * 4 + i) * 33 + ln] = aB1[r][i];
        }
        #pragma unroll
        for (int i = 0; i < 3; ++i) {
            const int dx = i * 4 + kg;
            if (dx < ND) {
                const int m  = ln;
                const int md = m + dx;
                const int idx = (md < 12) ? (m * 33 + md + 4)
                                          : (528 + m * 33 + md - 12);
                const float v = liv ? sw[idx] * scale : 0.0f;
                out[((((size_t)b * 81) + r * ND + dx) * H_ + (y0 + 1)) * W_ + X0 + m] = v;
            }
        }
    }
}

// ---- fallback: proven 76us scalar kernel (R11) if ws too small ----
__global__ __launch_bounds__(9 * 64, 3)
void corr_fallback(const float* __restrict__ t1,
                   const float* __restrict__ t2,
                   float* __restrict__ out) {
    const int tid  = threadIdx.x;
    const int lane = tid & 63;
    const int w    = tid >> 6;
    const int bid  = blockIdx.x;
    const int swz  = (bid & 7) * 32 + (bid >> 3);
    const int yp   = swz & 63;
    const int b    = swz >> 6;
    const int y0   = yp * 2;
    const int half = lane >> 5;
    const int lx   = lane & 31;
    const int x0   = lx * 8;
    const int yrow = y0 + half;
    const int yy   = yrow + w - MD;
    const bool live = (0 <= yy) && (yy < H_);
    const int  yc  = yy < 0 ? 0 : (yy > H_ - 1 ? H_ - 1 : yy);
    const float sc = live ? (1.0f / (float)C_) : 0.0f;
    const bool lm  = (lx == 0);
    const bool rm  = (lx == 31);
    const int offL = lm ? 0 : -4;
    const int offR = rm ? 0 :  8;

    float acc[ND][8];
    #pragma unroll
    for (int dx = 0; dx < ND; ++dx)
        #pragma unroll
        for (int j = 0; j < 8; ++j) acc[dx][j] = 0.0f;

    const float* p1 = t1 + (((size_t)(b * C_)) * H_ + yrow) * W_ + x0;
    const float* p2 = t2 + (((size_t)(b * C_)) * H_ + yc  ) * W_ + x0;
    const size_t chstr = (size_t)H_ * W_;

    #pragma unroll 2
    for (int c = 0; c < C_; ++c) {
        const float* pc1 = p1 + (size_t)c * chstr;
        const float* pc2 = p2 + (size_t)c * chstr;
        const float4v a0 = *(const float4v*)(pc1);
        const float4v a1 = *(const float4v*)(pc1 + 4);
        float4v wl = *(const float4v*)(pc2 + offL);
        const float4v v0 = *(const float4v*)(pc2);
        const float4v v1 = *(const float4v*)(pc2 + 4);
        float4v wr = *(const float4v*)(pc2 + offR);
        #pragma unroll
        for (int q = 0; q < 4; ++q) {
            wl[q] = lm ? 0.0f : wl[q];
            wr[q] = rm ? 0.0f : wr[q];
        }
        float win[16];
        #pragma unroll
        for (int q = 0; q < 4; ++q) {
            win[q] = wl[q]; win[4 + q] = v0[q];
            win[8 + q] = v1[q]; win[12 + q] = wr[q];
        }
        #pragma unroll
        for (int dx = 0; dx < ND; ++dx)
            #pragma unroll
            for (int j = 0; j < 8; ++j) {
                const float aj = (j < 4) ? a0[j] : a1[j - 4];
                acc[dx][j] = fmaf(aj, win[dx + j], acc[dx][j]);
            }
    }

    #pragma unroll
    for (int dx = 0; dx < ND; ++dx) {
        float4v o0, o1;
        #pragma unroll
        for (int j = 0; j < 4; ++j) {
            o0[j] = acc[dx][j] * sc;
            o1[j] = acc[dx][4 + j] * sc;
        }
        const size_t oidx =
            (((size_t)(b * ND * ND) + w * ND + dx) * H_ + yrow) * W_ + x0;
        *(float4v*)&out[oidx]     = o0;
        *(float4v*)&out[oidx + 4] = o1;
    }
}

extern "C" void kernel_launch(void* const* d_in, const int* in_sizes, int n_in,
                              void* d_out, int out_size, void* d_ws, size_t ws_size,
                              hipStream_t stream) {
    const float* t1 = (const float*)d_in[0];
    const float* t2 = (const float*)d_in[1];
    float* out      = (float*)d_out;
    const size_t need = TS * sizeof(unsigned short);   // 33.5 MB (t2 only)
    if (ws_size >= need) {
        unsigned short* ws = (unsigned short*)d_ws;
        convert_one<<<dim3(B_ * H_ * 4), 256, 0, stream>>>(t2, ws);
        corr_mfma6 <<<dim3(B_ * H_), 512, 0, stream>>>(t1, ws, out);
    } else {
        corr_fallback<<<dim3(B_ * H_ / 2), 9 * 64, 0, stream>>>(t1, t2, out);
    }
}

// Round 25
// 69.035 us; speedup vs baseline: 1.1964x; 1.0250x over previous
//
#include <hip/hip_runtime.h>

#define MD   4
#define B_   4
#define C_   128
#define H_   128
#define W_   256
#define ND   9

typedef float  float4v __attribute__((ext_vector_type(4)));
typedef float  f32x4   __attribute__((ext_vector_type(4)));
typedef short  bf16x8  __attribute__((ext_vector_type(8)));
typedef unsigned int u32;
typedef u32    u32x4   __attribute__((ext_vector_type(4)));

#define TS ((size_t)B_ * H_ * 4 * W_ * 32)   // halfs in converted t2

static __device__ __forceinline__ unsigned short f2bf(float f) {
    u32 u = __float_as_uint(f);
    u32 r = (u + 0x7fffu + ((u >> 16) & 1u)) >> 16;   // RNE
    return (unsigned short)r;
}

// ---- pass 1: t2 only -> bf16 ws (R19-exact body; L3-resident source) ----
__global__ __launch_bounds__(256, 2)
void convert_one(const float* __restrict__ src0,
                 unsigned short* __restrict__ dst0) {
    const int bid = blockIdx.x;          // [1:0]=kc [8:2]=y [10:9]=b
    const int kc  = bid & 3;
    const int y   = (bid >> 2) & (H_ - 1);
    const int b   = bid >> 9;
    const int x   = threadIdx.x;         // 0..255
    const float* src = src0 + ((size_t)(b * C_ + kc * 32) * H_ + y) * W_ + x;
    const size_t hw = (size_t)H_ * W_;

    float f[32];
    #pragma unroll
    for (int k = 0; k < 32; ++k) f[k] = src[(size_t)k * hw];

    unsigned short* dst =
        dst0 + ((((size_t)(b * H_ + y)) * 4 + kc) * W_ + x) * 32;
    #pragma unroll
    for (int q = 0; q < 4; ++q) {
        u32x4 pk;
        #pragma unroll
        for (int j = 0; j < 4; ++j)
            pk[j] = (u32)f2bf(f[q * 8 + 2 * j]) |
                    ((u32)f2bf(f[q * 8 + 2 * j + 1]) << 16);
        *(u32x4*)(dst + q * 8) = pk;
    }
}

// ---- pass 2: banded-Gram MFMA; A staged via LDS (block-cooperative) ----
// Per 32-ch chunk: 512 threads load t1's 32ch x 2row x 128col slab with 16
// fully-coalesced dword loads/thread-block-slice (thread(q=tid>>7,xl) +
// load i -> channel (i>>1)+8q, row i&1: each thread holds 8 CONSECUTIVE
// channels per row), f2bf in-register, ds_write_b128 to aS[buf][y][xl][k].
// Block A-VMEM: 64 instrs (vs 512 for the per-wave register path). Total
// block VMEM = 64+640+320 ~= mfma5's 1024 -> its 43us, without t1ws.
// B-loop + extraction verbatim from refcheck-passed R21/R24.
__global__ __launch_bounds__(512, 2)
void corr_mfma7(const float* __restrict__ t1,
                const unsigned short* __restrict__ t2w,
                float* __restrict__ out) {
    __shared__ float scr[8][2 * 16 * 33];              // 33792 B
    __shared__ __align__(16) unsigned short aS[2][2][128][32];  // 32768 B

    const int tid = threadIdx.x;
    const int l   = tid & 63;
    const int w   = tid >> 6;                  // 0..7
    const int bid = blockIdx.x;                // 512 blocks
    const int xcd = bid & 7;                   // 2-D XCD tiling
    const int xh  = xcd >> 2;                  // x half
    const int ypq = xcd & 3;                   // y-pair quarter
    const int rst = bid >> 3;                  // 0..63
    const int b   = rst >> 4;
    const int yp  = ypq * 16 + (rst & 15);
    const int y0  = yp * 2;
    const int ln  = l & 15;
    const int kg  = l >> 4;                    // 0..3
    const int X0  = (xh * 8 + w) * 16;         // this wave's x-tile
    const float scale = 1.0f / (float)C_;
    const bf16x8 z8 = (bf16x8)(short)0;
    const size_t hw = (size_t)H_ * W_;

    // staging identity for this thread: q selects k-octet, xl the column
    const int q  = tid >> 7;                   // 0..3
    const int xl = tid & 127;                  // 0..127

    f32x4 aA0[ND], aA1[ND], aB0[ND], aB1[ND];
    #pragma unroll
    for (int r = 0; r < ND; ++r) {
        aA0[r] = (f32x4)0.0f; aA1[r] = (f32x4)0.0f;
        aB0[r] = (f32x4)0.0f; aB1[r] = (f32x4)0.0f;
    }

    int col0 = X0 - 8 + ln;                    // B-tile 0 column (this lane)
    int col1 = X0 + 8 + ln;                    // B-tile 1 column
    const bool ob0 = col0 < 0;
    const bool ob1 = col1 > W_ - 1;
    col0 = ob0 ? 0 : col0;
    col1 = ob1 ? W_ - 1 : col1;

    // A-slab loads for chunk kc -> f[16] (all indices static after unroll)
    float f[16];
#define ALOAD(kc_)                                                          \
    {                                                                       \
        _Pragma("unroll")                                                   \
        for (int i = 0; i < 16; ++i) {                                      \
            const int cl = (i >> 1) + 8 * q;                                \
            const int yy_ = i & 1;                                          \
            f[i] = t1[((size_t)(b * C_ + (kc_) * 32 + cl) * H_              \
                       + y0 + yy_) * W_ + xh * 128 + xl];                   \
        }                                                                   \
    }
#define AWRITE(buf_)                                                        \
    {                                                                       \
        bf16x8 w0, w1;                                                      \
        _Pragma("unroll")                                                   \
        for (int j = 0; j < 8; ++j) {                                       \
            w0[j] = (short)f2bf(f[2 * j]);                                  \
            w1[j] = (short)f2bf(f[2 * j + 1]);                              \
        }                                                                   \
        *(bf16x8*)&aS[buf_][0][xl][q * 8] = w0;                             \
        *(bf16x8*)&aS[buf_][1][xl][q * 8] = w1;                             \
    }

    ALOAD(0);
    AWRITE(0);
    __syncthreads();                           // chunk 0 staged

    #pragma unroll
    for (int kc = 0; kc < 4; ++kc) {
        const int buf = kc & 1;
        if (kc < 3) ALOAD(kc + 1);             // next-slab loads in flight

        // A fragments from LDS (one b128 per y)
        const bf16x8 fA = *(const bf16x8*)&aS[buf][0][w * 16 + ln][kg * 8];
        const bf16x8 fB = *(const bf16x8*)&aS[buf][1][w * 16 + ln][kg * 8];

        #pragma unroll
        for (int r = 0; r < ND + 1; ++r) {     // staged rows y0-4 .. y0+5
            const int row = y0 + r - MD;       // wave-uniform
            if (0 <= row && row < H_) {
                const unsigned short* b_base =
                    t2w + ((((size_t)(b * H_ + row)) * 4 + kc) * W_) * 32;
                bf16x8 b0 = *(const bf16x8*)(b_base + (size_t)col0 * 32 + kg * 8);
                bf16x8 b1 = *(const bf16x8*)(b_base + (size_t)col1 * 32 + kg * 8);
                b0 = ob0 ? z8 : b0;            // zero-pad OOB x'
                b1 = ob1 ? z8 : b1;
                if (r < ND) {                  // feeds y0, dy=r
                    aA0[r] = __builtin_amdgcn_mfma_f32_16x16x32_bf16(fA, b0, aA0[r], 0, 0, 0);
                    aA1[r] = __builtin_amdgcn_mfma_f32_16x16x32_bf16(fA, b1, aA1[r], 0, 0, 0);
                }
                if (r >= 1) {                  // feeds y0+1, dy=r-1
                    aB0[r-1] = __builtin_amdgcn_mfma_f32_16x16x32_bf16(fB, b0, aB0[r-1], 0, 0, 0);
                    aB1[r-1] = __builtin_amdgcn_mfma_f32_16x16x32_bf16(fB, b1, aB1[r-1], 0, 0, 0);
                }
            }
        }

        if (kc < 3) AWRITE(buf ^ 1);           // safe: buf^1 last read at kc-1,
        __syncthreads();                       // barrier'd since
    }
#undef ALOAD
#undef AWRITE

    float* sw = scr[w];                        // T0 at [m*33+n], T1 at 528+..

    // ---- extraction pass 1: y0 (verbatim refcheck-passed) ----
    #pragma unroll
    for (int r = 0; r < ND; ++r) {
        const int row = y0 + r - MD;
        const bool liv = (0 <= row && row < H_);
        #pragma unroll
        for (int i = 0; i < 4; ++i) {
            sw[(kg * 4 + i) * 33 + ln]       = aA0[r][i];
            sw[528 + (kg * 4 + i) * 33 + ln] = aA1[r][i];
        }
        #pragma unroll
        for (int i = 0; i < 3; ++i) {
            const int dx = i * 4 + kg;
            if (dx < ND) {
                const int m  = ln;
                const int md = m + dx;
                const int idx = (md < 12) ? (m * 33 + md + 4)
                                          : (528 + m * 33 + md - 12);
                const float v = liv ? sw[idx] * scale : 0.0f;
                out[((((size_t)b * 81) + r * ND + dx) * H_ + y0) * W_ + X0 + m] = v;
            }
        }
    }
    // ---- extraction pass 2: y0+1 ----
    #pragma unroll
    for (int r = 0; r < ND; ++r) {
        const int row = y0 + 1 + r - MD;
        const bool liv = (0 <= row && row < H_);
        #pragma unroll
        for (int i = 0; i < 4; ++i) {
            sw[(kg * 4 + i) * 33 + ln]       = aB0[r][i];
            sw[528 + (kg * 4 + i) * 33 + ln] = aB1[r][i];
        }
        #pragma unroll
        for (int i = 0; i < 3; ++i) {
            const int dx = i * 4 + kg;
            if (dx < ND) {
                const int m  = ln;
                const int md = m + dx;
                const int idx = (md < 12) ? (m * 33 + md + 4)
                                          : (528 + m * 33 + md - 12);
                const float v = liv ? sw[idx] * scale : 0.0f;
                out[((((size_t)b * 81) + r * ND + dx) * H_ + (y0 + 1)) * W_ + X0 + m] = v;
            }
        }
    }
}

// ---- fallback: proven 76us scalar kernel (R11) if ws too small ----
__global__ __launch_bounds__(9 * 64, 3)
void corr_fallback(const float* __restrict__ t1,
                   const float* __restrict__ t2,
                   float* __restrict__ out) {
    const int tid  = threadIdx.x;
    const int lane = tid & 63;
    const int w    = tid >> 6;
    const int bid  = blockIdx.x;
    const int swz  = (bid & 7) * 32 + (bid >> 3);
    const int yp   = swz & 63;
    const int b    = swz >> 6;
    const int y0   = yp * 2;
    const int half = lane >> 5;
    const int lx   = lane & 31;
    const int x0   = lx * 8;
    const int yrow = y0 + half;
    const int yy   = yrow + w - MD;
    const bool live = (0 <= yy) && (yy < H_);
    const int  yc  = yy < 0 ? 0 : (yy > H_ - 1 ? H_ - 1 : yy);
    const float sc = live ? (1.0f / (float)C_) : 0.0f;
    const bool lm  = (lx == 0);
    const bool rm  = (lx == 31);
    const int offL = lm ? 0 : -4;
    const int offR = rm ? 0 :  8;

    float acc[ND][8];
    #pragma unroll
    for (int dx = 0; dx < ND; ++dx)
        #pragma unroll
        for (int j = 0; j < 8; ++j) acc[dx][j] = 0.0f;

    const float* p1 = t1 + (((size_t)(b * C_)) * H_ + yrow) * W_ + x0;
    const float* p2 = t2 + (((size_t)(b * C_)) * H_ + yc  ) * W_ + x0;
    const size_t chstr = (size_t)H_ * W_;

    #pragma unroll 2
    for (int c = 0; c < C_; ++c) {
        const float* pc1 = p1 + (size_t)c * chstr;
        const float* pc2 = p2 + (size_t)c * chstr;
        const float4v a0 = *(const float4v*)(pc1);
        const float4v a1 = *(const float4v*)(pc1 + 4);
        float4v wl = *(const float4v*)(pc2 + offL);
        const float4v v0 = *(const float4v*)(pc2);
        const float4v v1 = *(const float4v*)(pc2 + 4);
        float4v wr = *(const float4v*)(pc2 + offR);
        #pragma unroll
        for (int qq = 0; qq < 4; ++qq) {
            wl[qq] = lm ? 0.0f : wl[qq];
            wr[qq] = rm ? 0.0f : wr[qq];
        }
        float win[16];
        #pragma unroll
        for (int qq = 0; qq < 4; ++qq) {
            win[qq] = wl[qq]; win[4 + qq] = v0[qq];
            win[8 + qq] = v1[qq]; win[12 + qq] = wr[qq];
        }
        #pragma unroll
        for (int dx = 0; dx < ND; ++dx)
            #pragma unroll
            for (int j = 0; j < 8; ++j) {
                const float aj = (j < 4) ? a0[j] : a1[j - 4];
                acc[dx][j] = fmaf(aj, win[dx + j], acc[dx][j]);
            }
    }

    #pragma unroll
    for (int dx = 0; dx < ND; ++dx) {
        float4v o0, o1;
        #pragma unroll
        for (int j = 0; j < 4; ++j) {
            o0[j] = acc[dx][j] * sc;
            o1[j] = acc[dx][4 + j] * sc;
        }
        const size_t oidx =
            (((size_t)(b * ND * ND) + w * ND + dx) * H_ + yrow) * W_ + x0;
        *(float4v*)&out[oidx]     = o0;
        *(float4v*)&out[oidx + 4] = o1;
    }
}

extern "C" void kernel_launch(void* const* d_in, const int* in_sizes, int n_in,
                              void* d_out, int out_size, void* d_ws, size_t ws_size,
                              hipStream_t stream) {
    const float* t1 = (const float*)d_in[0];
    const float* t2 = (const float*)d_in[1];
    float* out      = (float*)d_out;
    const size_t need = TS * sizeof(unsigned short);   // 33.5 MB (t2 only)
    if (ws_size >= need) {
        unsigned short* ws = (unsigned short*)d_ws;
        convert_one<<<dim3(B_ * H_ * 4), 256, 0, stream>>>(t2, ws);
        corr_mfma7 <<<dim3(B_ * H_), 512, 0, stream>>>(t1, ws, out);
    } else {
        corr_fallback<<<dim3(B_ * H_ / 2), 9 * 64, 0, stream>>>(t1, t2, out);
    }
}